// Round 1
// baseline (1172.575 us; speedup 1.0000x reference)
//
#include <hip/hip_runtime.h>
#include <math.h>

// MAMBAFlow fp32 implementation.
// B=16, NS=NQ=1024, N=2048 tokens, D=256, L=4 layers, S=8 states, H=4 heads, hd=64.
// All compute fp32 (no fp32 MFMA on CDNA4; threshold is ~2% of tiny outputs, so
// round 0 stays exact). Structure:
//   embed -> 4x [LN+Bu, wave-parallel scan, gate GEMM w/ fused SSM epilogue]
//   -> QKV GEMMs -> tiled flash attention -> out proj -> dec1(relu) -> dec2 dot.

__device__ __forceinline__ float wave_sum64(float v) {
#pragma unroll
  for (int m = 1; m < 64; m <<= 1) v += __shfl_xor(v, m);
  return v;
}

// ---------------- embed: fourier feats + input proj + time embed ----------------
__global__ __launch_bounds__(256) void embed_k(
    const float* __restrict__ sc, const float* __restrict__ sv,
    const float* __restrict__ qc, const float* __restrict__ tarr,
    const float* __restrict__ noise, const float* __restrict__ Bf,
    const float* __restrict__ Wq, const float* __restrict__ bq,
    const float* __restrict__ Wi, const float* __restrict__ bi,
    float* __restrict__ seq) {
  int tok = blockIdx.x;          // 0 .. 16*2048-1
  int b = tok >> 11, n = tok & 2047;
  int tid = threadIdx.x;
  bool isq = (n >= 1024);
  int nn = isq ? n - 1024 : n;
  const float* cp = (isq ? qc : sc) + (size_t)(b * 1024 + nn) * 2;
  __shared__ float f[33];
  if (tid < 16) {
    float px = cp[0] * Bf[tid] + cp[1] * Bf[16 + tid];
    f[tid] = sinf(px);
    f[16 + tid] = cosf(px);
  } else if (tid == 16) {
    f[32] = (isq ? noise : sv)[b * 1024 + nn];
  }
  __syncthreads();
  const float* W = (isq ? Wq : Wi) + tid * 33;
  float acc = (isq ? bq : bi)[tid];
#pragma unroll
  for (int c = 0; c < 33; ++c) acc += f[c] * W[c];
  // time embedding: half=128, freqs = exp(i * -ln(1e4)/127)
  float t = tarr[b];
  int dd = (tid < 128) ? tid : tid - 128;
  float e = t * expf((float)dd * -0.07252236513367074f);
  acc += (tid < 128) ? sinf(e) : cosf(e);
  seq[(size_t)tok * 256 + tid] = acc;
}

// ---------------- layernorm + Bu = xn @ Bw^T ----------------
__global__ __launch_bounds__(256) void ln_bu_k(
    const float* __restrict__ seq, const float* __restrict__ g,
    const float* __restrict__ be, const float* __restrict__ Bw,
    float* __restrict__ xn, float* __restrict__ Bu) {
  int m = blockIdx.x, tid = threadIdx.x;
  __shared__ float ws1[4], ws2[4];
  __shared__ float xs[256];
  float x = seq[(size_t)m * 256 + tid];
  float s1 = x, s2 = x * x;
#pragma unroll
  for (int mk = 1; mk < 64; mk <<= 1) {
    s1 += __shfl_xor(s1, mk);
    s2 += __shfl_xor(s2, mk);
  }
  if ((tid & 63) == 0) { ws1[tid >> 6] = s1; ws2[tid >> 6] = s2; }
  __syncthreads();
  float mu = (ws1[0] + ws1[1] + ws1[2] + ws1[3]) * (1.0f / 256.0f);
  float ms = (ws2[0] + ws2[1] + ws2[2] + ws2[3]) * (1.0f / 256.0f);
  float var = ms - mu * mu;
  float v = (x - mu) * rsqrtf(var + 1e-5f) * g[tid] + be[tid];
  xn[(size_t)m * 256 + tid] = v;
  xs[tid] = v;
  __syncthreads();
  int s = tid >> 5, l32 = tid & 31;   // 8 state dims x 32 lanes each
  const float* bw = Bw + s * 256;
  float p = 0.f;
#pragma unroll
  for (int i = 0; i < 8; ++i) p += xs[l32 + 32 * i] * bw[l32 + 32 * i];
#pragma unroll
  for (int mk = 1; mk < 32; mk <<= 1) p += __shfl_xor(p, mk);
  if (l32 == 0) Bu[(size_t)m * 8 + s] = p;
}

// ---------------- SSM scan: one wave per (b,s); chunk-compose + shuffle scan ----------------
__global__ __launch_bounds__(256) void scan_k(
    const float* __restrict__ Bu, const float* __restrict__ A_log,
    float* __restrict__ hs) {
  int tid = threadIdx.x;
  int wid = blockIdx.x * 4 + (tid >> 6);  // 0..127 = b*8 + s
  int lane = tid & 63;
  int b = wid >> 3, s = wid & 7;
  float A = -fminf(fmaxf(expf(A_log[s]), 1e-8f), 10.0f);
  float abar = expf(A * (1.0f / 2048.0f));
  const float* bu = Bu + ((size_t)(b * 2048 + lane * 32)) * 8 + s;
  // local chunk (32 steps) transform: h_out = aL*h_in + bl
  float bl = 0.f;
#pragma unroll
  for (int k = 0; k < 32; ++k) bl = abar * bl + bu[(size_t)k * 8];
  float a = expf(A * (32.0f / 2048.0f));
  float bb = bl;
  // inclusive Hillis-Steele scan of transform composition across lanes
#pragma unroll
  for (int off = 1; off < 64; off <<= 1) {
    float pa = __shfl_up(a, (unsigned)off);
    float pb = __shfl_up(bb, (unsigned)off);
    if (lane >= off) { bb = a * pb + bb; a = a * pa; }
  }
  float hin = __shfl_up(bb, 1u);
  if (lane == 0) hin = 0.f;
  // replay with correct incoming state
  float h = hin;
  float* hp = hs + ((size_t)(b * 2048 + lane * 32)) * 8 + s;
#pragma unroll
  for (int k = 0; k < 32; ++k) {
    h = abar * h + bu[(size_t)k * 8];
    hp[(size_t)k * 8] = h;
  }
}

// ---------------- generic 64x64-tile fp32 GEMM: C = A @ W^T (+bias, +act / gate-SSM epilogue) ----------------
// MODE 0: C = acc + bias       MODE 1: relu(acc + bias)
// MODE 2: seq += sigmoid(acc + gate_b) * (Dp*xn + hs @ Cw^T)   (C = seq, A = xn)
template <int MODE>
__global__ __launch_bounds__(256) void gemm_k(
    const float* __restrict__ A, const float* __restrict__ W,
    const float* __restrict__ bias, float* __restrict__ C, int ldc,
    int aClog, int aStride, int aBase,
    const float* __restrict__ hsb, const float* __restrict__ Cw,
    const float* __restrict__ Dp) {
  __shared__ float As[16 * 68];  // [k][m], pad 4
  __shared__ float Bs[16 * 68];  // [k][n]
  int tid = threadIdx.x;
  int n0 = blockIdx.x * 64, m0 = blockIdx.y * 64;
  int lr = tid >> 2, lq = tid & 3;
  int am = m0 + lr;
  int arow = ((am >> aClog) * aStride) + aBase + (am & (int)((1u << aClog) - 1u));
  const float* pA = A + (size_t)arow * 256 + lq * 4;
  const float* pW = W + (size_t)(n0 + lr) * 256 + lq * 4;
  int tx = tid & 15, ty = tid >> 4;
  float acc[4][4] = {};
  for (int kt = 0; kt < 16; ++kt) {
    float4 av = *(const float4*)(pA + kt * 16);
    float4 wv = *(const float4*)(pW + kt * 16);
    __syncthreads();
    As[(lq * 4 + 0) * 68 + lr] = av.x;
    As[(lq * 4 + 1) * 68 + lr] = av.y;
    As[(lq * 4 + 2) * 68 + lr] = av.z;
    As[(lq * 4 + 3) * 68 + lr] = av.w;
    Bs[(lq * 4 + 0) * 68 + lr] = wv.x;
    Bs[(lq * 4 + 1) * 68 + lr] = wv.y;
    Bs[(lq * 4 + 2) * 68 + lr] = wv.z;
    Bs[(lq * 4 + 3) * 68 + lr] = wv.w;
    __syncthreads();
#pragma unroll
    for (int k = 0; k < 16; ++k) {
      float4 a4 = *(const float4*)(As + k * 68 + ty * 4);
      float4 b4 = *(const float4*)(Bs + k * 68 + tx * 4);
      float aa[4] = {a4.x, a4.y, a4.z, a4.w};
      float bv[4] = {b4.x, b4.y, b4.z, b4.w};
#pragma unroll
      for (int i = 0; i < 4; ++i)
#pragma unroll
        for (int j = 0; j < 4; ++j) acc[i][j] += aa[i] * bv[j];
    }
  }
  int colBase = n0 + tx * 4;
  if (MODE == 2) {
#pragma unroll
    for (int i = 0; i < 4; ++i) {
      int m = m0 + ty * 4 + i;
      float4 h0 = *(const float4*)(hsb + (size_t)m * 8);
      float4 h1 = *(const float4*)(hsb + (size_t)m * 8 + 4);
      float4 xv4 = *(const float4*)(A + (size_t)m * 256 + colBase);  // A == xn (dense)
      float* srow = C + (size_t)m * 256 + colBase;
      float4 sv4 = *(const float4*)srow;
      float xv[4] = {xv4.x, xv4.y, xv4.z, xv4.w};
      float sv[4] = {sv4.x, sv4.y, sv4.z, sv4.w};
      float outv[4];
#pragma unroll
      for (int j = 0; j < 4; ++j) {
        int jj = colBase + j;
        float gt = 1.0f / (1.0f + expf(-(acc[i][j] + bias[jj])));
        float4 c0 = *(const float4*)(Cw + (size_t)jj * 8);
        float4 c1 = *(const float4*)(Cw + (size_t)jj * 8 + 4);
        float y = Dp[jj] * xv[j]
                + h0.x * c0.x + h0.y * c0.y + h0.z * c0.z + h0.w * c0.w
                + h1.x * c1.x + h1.y * c1.y + h1.z * c1.z + h1.w * c1.w;
        outv[j] = sv[j] + gt * y;
      }
      *(float4*)srow = make_float4(outv[0], outv[1], outv[2], outv[3]);
    }
  } else {
#pragma unroll
    for (int i = 0; i < 4; ++i) {
      int m = m0 + ty * 4 + i;
      float outv[4];
#pragma unroll
      for (int j = 0; j < 4; ++j) {
        float v = acc[i][j] + bias[colBase + j];
        if (MODE == 1) v = fmaxf(v, 0.f);
        outv[j] = v;
      }
      *(float4*)(C + (size_t)m * ldc + colBase) = make_float4(outv[0], outv[1], outv[2], outv[3]);
    }
  }
}

// ---------------- tiled flash attention: block = (b, h, 64 q rows) ----------------
__global__ __launch_bounds__(256) void attn_k(const float* __restrict__ qb,
                                              const float* __restrict__ kvb,
                                              float* __restrict__ ob) {
  __shared__ float Qs[64 * 68];   // [d][q] (transposed)
  __shared__ float KPs[64 * 68];  // K transposed [d][k]; reused for P [q][k]
  __shared__ float Vs[64 * 68];   // [k][d]
  int tid = threadIdx.x;
  int bid = blockIdx.x;  // 16 qtiles * 4 heads * 16 batch = 1024
  int qt = bid & 15, bh = bid >> 4;
  int h = bh & 3, b = bh >> 2;
  int lr = tid >> 2, lq = tid & 3;
  {
    const float* qrow = qb + ((size_t)(b * 1024 + qt * 64 + lr)) * 256 + h * 64;
#pragma unroll
    for (int rep = 0; rep < 4; ++rep) {
      int c4 = rep * 4 + lq;
      float4 v = *(const float4*)(qrow + c4 * 4);
      Qs[(c4 * 4 + 0) * 68 + lr] = v.x * 0.125f;  // 1/sqrt(64) folded in
      Qs[(c4 * 4 + 1) * 68 + lr] = v.y * 0.125f;
      Qs[(c4 * 4 + 2) * 68 + lr] = v.z * 0.125f;
      Qs[(c4 * 4 + 3) * 68 + lr] = v.w * 0.125f;
    }
  }
  int tx = tid & 15, ty = tid >> 4;
  float m_i[4], l_i[4], o[4][4];
#pragma unroll
  for (int i = 0; i < 4; ++i) {
    m_i[i] = -3.0e38f;
    l_i[i] = 0.f;
#pragma unroll
    for (int j = 0; j < 4; ++j) o[i][j] = 0.f;
  }
  const float* kvbase = kvb + ((size_t)(b * 1024)) * 512 + h * 64;
  for (int kt = 0; kt < 16; ++kt) {
    __syncthreads();  // prior PV reads done before restaging
    {
      const float* krow = kvbase + (size_t)(kt * 64 + lr) * 512;
#pragma unroll
      for (int rep = 0; rep < 4; ++rep) {
        int c4 = rep * 4 + lq;
        float4 kk = *(const float4*)(krow + c4 * 4);
        KPs[(c4 * 4 + 0) * 68 + lr] = kk.x;
        KPs[(c4 * 4 + 1) * 68 + lr] = kk.y;
        KPs[(c4 * 4 + 2) * 68 + lr] = kk.z;
        KPs[(c4 * 4 + 3) * 68 + lr] = kk.w;
        float4 vv = *(const float4*)(krow + 256 + c4 * 4);
        *(float4*)(Vs + (size_t)lr * 68 + c4 * 4) = vv;
      }
    }
    __syncthreads();
    float s[4][4] = {};
#pragma unroll 16
    for (int d = 0; d < 64; ++d) {
      float4 q4 = *(const float4*)(Qs + d * 68 + ty * 4);
      float4 k4 = *(const float4*)(KPs + d * 68 + tx * 4);
      float qa[4] = {q4.x, q4.y, q4.z, q4.w};
      float ka[4] = {k4.x, k4.y, k4.z, k4.w};
#pragma unroll
      for (int i = 0; i < 4; ++i)
#pragma unroll
        for (int j = 0; j < 4; ++j) s[i][j] += qa[i] * ka[j];
    }
    float p[4][4], alpha[4], rs[4];
#pragma unroll
    for (int i = 0; i < 4; ++i) {
      float rm = fmaxf(fmaxf(s[i][0], s[i][1]), fmaxf(s[i][2], s[i][3]));
#pragma unroll
      for (int mk = 1; mk < 16; mk <<= 1) rm = fmaxf(rm, __shfl_xor(rm, mk));
      float mnew = fmaxf(m_i[i], rm);
      alpha[i] = expf(m_i[i] - mnew);
      m_i[i] = mnew;
      float lsum = 0.f;
#pragma unroll
      for (int j = 0; j < 4; ++j) {
        p[i][j] = expf(s[i][j] - mnew);
        lsum += p[i][j];
      }
#pragma unroll
      for (int mk = 1; mk < 16; mk <<= 1) lsum += __shfl_xor(lsum, mk);
      rs[i] = lsum;
    }
    __syncthreads();  // all K reads done before P overwrites KPs
#pragma unroll
    for (int i = 0; i < 4; ++i) {
      l_i[i] = l_i[i] * alpha[i] + rs[i];
#pragma unroll
      for (int j = 0; j < 4; ++j) o[i][j] *= alpha[i];
      *(float4*)(KPs + (size_t)(ty * 4 + i) * 68 + tx * 4) =
          make_float4(p[i][0], p[i][1], p[i][2], p[i][3]);
    }
    __syncthreads();
#pragma unroll 4
    for (int k0 = 0; k0 < 64; k0 += 4) {
      float4 pr[4], vr[4];
#pragma unroll
      for (int i = 0; i < 4; ++i)
        pr[i] = *(const float4*)(KPs + (size_t)(ty * 4 + i) * 68 + k0);
#pragma unroll
      for (int kk = 0; kk < 4; ++kk)
        vr[kk] = *(const float4*)(Vs + (size_t)(k0 + kk) * 68 + tx * 4);
      float vm[4][4];
#pragma unroll
      for (int kk = 0; kk < 4; ++kk) {
        vm[kk][0] = vr[kk].x; vm[kk][1] = vr[kk].y;
        vm[kk][2] = vr[kk].z; vm[kk][3] = vr[kk].w;
      }
#pragma unroll
      for (int i = 0; i < 4; ++i) {
        float pa[4] = {pr[i].x, pr[i].y, pr[i].z, pr[i].w};
#pragma unroll
        for (int j = 0; j < 4; ++j)
          o[i][j] += pa[0] * vm[0][j] + pa[1] * vm[1][j] + pa[2] * vm[2][j] + pa[3] * vm[3][j];
      }
    }
  }
#pragma unroll
  for (int i = 0; i < 4; ++i) {
    float inv = 1.0f / l_i[i];
    *(float4*)(ob + ((size_t)(b * 1024 + qt * 64 + ty * 4 + i)) * 256 + h * 64 + tx * 4) =
        make_float4(o[i][0] * inv, o[i][1] * inv, o[i][2] * inv, o[i][3] * inv);
  }
}

// ---------------- final 1-dim projection ----------------
__global__ __launch_bounds__(256) void dec2_k(const float* __restrict__ hb,
                                              const float* __restrict__ w2,
                                              const float* __restrict__ b2,
                                              float* __restrict__ out) {
  int tid = threadIdx.x;
  int m = blockIdx.x * 4 + (tid >> 6);
  int lane = tid & 63;
  float4 h4 = *(const float4*)(hb + (size_t)m * 256 + lane * 4);
  float4 w4 = *(const float4*)(w2 + lane * 4);
  float v = h4.x * w4.x + h4.y * w4.y + h4.z * w4.z + h4.w * w4.w;
  v = wave_sum64(v);
  if (lane == 0) out[m] = v + b2[0];
}

extern "C" void kernel_launch(void* const* d_in, const int* in_sizes, int n_in,
                              void* d_out, int out_size, void* d_ws, size_t ws_size,
                              hipStream_t stream) {
  const float* sparse_coords = (const float*)d_in[0];
  const float* sparse_values = (const float*)d_in[1];
  const float* query_coords  = (const float*)d_in[2];
  const float* t_arr         = (const float*)d_in[3];
  const float* noise         = (const float*)d_in[4];
  const float* B_f           = (const float*)d_in[5];
  const float* Wq_in         = (const float*)d_in[6];
  const float* bq_in         = (const float*)d_in[7];
  const float* Wi_in         = (const float*)d_in[8];
  const float* bi_in         = (const float*)d_in[9];
  const float* A_log         = (const float*)d_in[10];
  const float* Bw            = (const float*)d_in[11];
  const float* Cw            = (const float*)d_in[12];
  const float* Dp            = (const float*)d_in[13];
  const float* ln_g          = (const float*)d_in[14];
  const float* ln_b          = (const float*)d_in[15];
  const float* gate_w        = (const float*)d_in[16];
  const float* gate_b        = (const float*)d_in[17];
  const float* in_proj_w     = (const float*)d_in[18];
  const float* in_proj_b     = (const float*)d_in[19];
  const float* out_w         = (const float*)d_in[20];
  const float* out_b         = (const float*)d_in[21];
  const float* dec_w1        = (const float*)d_in[22];
  const float* dec_b1        = (const float*)d_in[23];
  const float* dec_w2        = (const float*)d_in[24];
  const float* dec_b2        = (const float*)d_in[25];

  float* ws = (float*)d_ws;
  float* seq = ws;                       // 16*2048*256 = 8,388,608
  float* xn  = seq + 8388608;            // 8,388,608
  float* kv  = xn + 8388608;             // 16*1024*512 = 8,388,608
  float* qb  = kv + 8388608;             // 16*1024*256 = 4,194,304
  float* ob  = qb + 4194304;             // 4,194,304
  float* Bu  = ob + 4194304;             // 16*2048*8 = 262,144
  float* hsb = Bu + 262144;              // 262,144
  float* attended = xn;                  // xn dead after layer loop
  float* hrelu    = xn + 4194304;

  embed_k<<<32768, 256, 0, stream>>>(sparse_coords, sparse_values, query_coords,
                                     t_arr, noise, B_f, Wq_in, bq_in, Wi_in, bi_in, seq);
  for (int l = 0; l < 4; ++l) {
    ln_bu_k<<<32768, 256, 0, stream>>>(seq, ln_g + l * 256, ln_b + l * 256,
                                       Bw + l * 2048, xn, Bu);
    scan_k<<<32, 256, 0, stream>>>(Bu, A_log + l * 8, hsb);
    gemm_k<2><<<dim3(4, 512), 256, 0, stream>>>(
        xn, gate_w + l * 65536, gate_b + l * 256, seq, 256,
        30, 0, 0, hsb, Cw + l * 2048, Dp + l * 256);
  }
  // Q from query half (rows 1024..2047 of each batch)
  gemm_k<0><<<dim3(4, 256), 256, 0, stream>>>(
      seq, in_proj_w, in_proj_b, qb, 256, 10, 2048, 1024, nullptr, nullptr, nullptr);
  // K|V from input half (rows 0..1023), fused 512-wide output
  gemm_k<0><<<dim3(8, 256), 256, 0, stream>>>(
      seq, in_proj_w + 65536, in_proj_b + 256, kv, 512, 10, 2048, 0, nullptr, nullptr, nullptr);
  attn_k<<<1024, 256, 0, stream>>>(qb, kv, ob);
  gemm_k<0><<<dim3(4, 256), 256, 0, stream>>>(
      ob, out_w, out_b, attended, 256, 30, 0, 0, nullptr, nullptr, nullptr);
  gemm_k<1><<<dim3(4, 256), 256, 0, stream>>>(
      attended, dec_w1, dec_b1, hrelu, 256, 30, 0, 0, nullptr, nullptr, nullptr);
  dec2_k<<<4096, 256, 0, stream>>>(hrelu, dec_w2, dec_b2, (float*)d_out);
}

// Round 3
// 868.256 us; speedup vs baseline: 1.3505x; 1.3505x over previous
//
#include <hip/hip_runtime.h>
#include <math.h>

// MAMBAFlow split-bf16 MFMA implementation.
// B=16, N=2048 tok, D=256, L=4, S=8, H=4 heads, hd=64.
// All matmuls on mfma_f32_16x16x32_bf16 with 2-term bf16 splits (hi+lo):
//   a*b ~= ahi*bhi + ahi*blo + alo*bhi   (~2^-17 relative error)
// Activations stay fp32 in global; splits happen during LDS staging.
// Only P,V in the attention P*V product are single-bf16 (error averages out).

typedef float floatx4 __attribute__((ext_vector_type(4)));
typedef short shortx8 __attribute__((ext_vector_type(8)));

__device__ __forceinline__ unsigned short f2bf(float f) {
  unsigned u = __builtin_bit_cast(unsigned, f);
  u += 0x7FFFu + ((u >> 16) & 1u);  // RNE
  return (unsigned short)(u >> 16);
}
__device__ __forceinline__ float bf2f(unsigned short h) {
  unsigned u = ((unsigned)h) << 16;
  return __builtin_bit_cast(float, u);
}
// split 8 consecutive floats into hi/lo bf16 packs
__device__ __forceinline__ void split8(float4 a, float4 b, uint4& uh, uint4& ul) {
  float fv[8] = {a.x, a.y, a.z, a.w, b.x, b.y, b.z, b.w};
  unsigned hh[8], ll[8];
#pragma unroll
  for (int j = 0; j < 8; ++j) {
    unsigned short h = f2bf(fv[j]);
    hh[j] = h;
    ll[j] = f2bf(fv[j] - bf2f(h));
  }
  uh = make_uint4(hh[0] | (hh[1] << 16), hh[2] | (hh[3] << 16),
                  hh[4] | (hh[5] << 16), hh[6] | (hh[7] << 16));
  ul = make_uint4(ll[0] | (ll[1] << 16), ll[2] | (ll[3] << 16),
                  ll[4] | (ll[5] << 16), ll[6] | (ll[7] << 16));
}
__device__ __forceinline__ shortx8 lds_frag(const unsigned short* S, int row, int u) {
  uint4 v = *(const uint4*)(S + row * 64 + ((u ^ (row & 7)) << 3));
  return __builtin_bit_cast(shortx8, v);
}
__device__ __forceinline__ floatx4 mfma16(shortx8 a, shortx8 b, floatx4 c) {
  return __builtin_amdgcn_mfma_f32_16x16x32_bf16(a, b, c, 0, 0, 0);
}
__device__ __forceinline__ float wave_sum64(float v) {
#pragma unroll
  for (int m = 1; m < 64; m <<= 1) v += __shfl_xor(v, m);
  return v;
}

// ---------------- embed: fourier feats + input proj + time embed ----------------
__global__ __launch_bounds__(256) void embed_k(
    const float* __restrict__ sc, const float* __restrict__ sv,
    const float* __restrict__ qc, const float* __restrict__ tarr,
    const float* __restrict__ noise, const float* __restrict__ Bf,
    const float* __restrict__ Wq, const float* __restrict__ bq,
    const float* __restrict__ Wi, const float* __restrict__ bi,
    float* __restrict__ seq) {
  int tok = blockIdx.x;
  int b = tok >> 11, n = tok & 2047;
  int tid = threadIdx.x;
  bool isq = (n >= 1024);
  int nn = isq ? n - 1024 : n;
  const float* cp = (isq ? qc : sc) + (size_t)(b * 1024 + nn) * 2;
  __shared__ float f[33];
  if (tid < 16) {
    float px = cp[0] * Bf[tid] + cp[1] * Bf[16 + tid];
    f[tid] = sinf(px);
    f[16 + tid] = cosf(px);
  } else if (tid == 16) {
    f[32] = (isq ? noise : sv)[b * 1024 + nn];
  }
  __syncthreads();
  const float* W = (isq ? Wq : Wi) + tid * 33;
  float acc = (isq ? bq : bi)[tid];
#pragma unroll
  for (int c = 0; c < 33; ++c) acc += f[c] * W[c];
  float t = tarr[b];
  int dd = (tid < 128) ? tid : tid - 128;
  float e = t * expf((float)dd * -0.07252236513367074f);
  acc += (tid < 128) ? sinf(e) : cosf(e);
  seq[(size_t)tok * 256 + tid] = acc;
}

// ---------------- layernorm (wave per row) + fp32 xn + Bu ----------------
__global__ __launch_bounds__(256) void ln_bu_k(
    const float* __restrict__ seq, const float* __restrict__ g,
    const float* __restrict__ be, const float* __restrict__ Bw,
    float* __restrict__ xn, float* __restrict__ Bu) {
  int tid = threadIdx.x;
  int row = blockIdx.x * 4 + (tid >> 6);
  int lane = tid & 63;
  float4 x = *(const float4*)(seq + (size_t)row * 256 + lane * 4);
  float s1 = x.x + x.y + x.z + x.w;
  float s2 = x.x * x.x + x.y * x.y + x.z * x.z + x.w * x.w;
#pragma unroll
  for (int mk = 1; mk < 64; mk <<= 1) {
    s1 += __shfl_xor(s1, mk);
    s2 += __shfl_xor(s2, mk);
  }
  float mu = s1 * (1.0f / 256.0f);
  float var = s2 * (1.0f / 256.0f) - mu * mu;
  float rs = rsqrtf(var + 1e-5f);
  float4 gg = *(const float4*)(g + lane * 4);
  float4 bb = *(const float4*)(be + lane * 4);
  float xn0 = (x.x - mu) * rs * gg.x + bb.x;
  float xn1 = (x.y - mu) * rs * gg.y + bb.y;
  float xn2 = (x.z - mu) * rs * gg.z + bb.z;
  float xn3 = (x.w - mu) * rs * gg.w + bb.w;
  *(float4*)(xn + (size_t)row * 256 + lane * 4) = make_float4(xn0, xn1, xn2, xn3);
#pragma unroll
  for (int s = 0; s < 8; ++s) {
    float4 bw = *(const float4*)(Bw + s * 256 + lane * 4);
    float p = xn0 * bw.x + xn1 * bw.y + xn2 * bw.z + xn3 * bw.w;
#pragma unroll
    for (int mk = 1; mk < 64; mk <<= 1) p += __shfl_xor(p, mk);
    if (lane == 0) Bu[(size_t)row * 8 + s] = p;
  }
}

// ---------------- SSM scan: one wave per (b,s) ----------------
__global__ __launch_bounds__(256) void scan_k(
    const float* __restrict__ Bu, const float* __restrict__ A_log,
    float* __restrict__ hs) {
  int tid = threadIdx.x;
  int wid = blockIdx.x * 4 + (tid >> 6);
  int lane = tid & 63;
  int b = wid >> 3, s = wid & 7;
  float A = -fminf(fmaxf(expf(A_log[s]), 1e-8f), 10.0f);
  float abar = expf(A * (1.0f / 2048.0f));
  const float* bu = Bu + ((size_t)(b * 2048 + lane * 32)) * 8 + s;
  float bl = 0.f;
#pragma unroll
  for (int k = 0; k < 32; ++k) bl = abar * bl + bu[(size_t)k * 8];
  float a = expf(A * (32.0f / 2048.0f));
  float bb = bl;
#pragma unroll
  for (int off = 1; off < 64; off <<= 1) {
    float pa = __shfl_up(a, (unsigned)off);
    float pb = __shfl_up(bb, (unsigned)off);
    if (lane >= off) { bb = a * pb + bb; a = a * pa; }
  }
  float hin = __shfl_up(bb, 1u);
  if (lane == 0) hin = 0.f;
  float h = hin;
  float* hp = hs + ((size_t)(b * 2048 + lane * 32)) * 8 + s;
#pragma unroll
  for (int k = 0; k < 32; ++k) {
    h = abar * h + bu[(size_t)k * 8];
    hp[(size_t)k * 8] = h;
  }
}

// ---------------- split-bf16 MFMA GEMM: C = A(fp32,Mx256) @ W([N][256])^T ----------------
// MODE 0: fp32 out = acc+bias   MODE 1: fp32 out = relu(acc+bias)
// MODE 2: seq(fp32) += sigmoid(acc+bias) * (Dp*xn + hs @ Cw^T)
template <int MODE>
__global__ __launch_bounds__(256, 2) void mgemm_k(
    const float* __restrict__ A,
    const unsigned short* __restrict__ Wh, const unsigned short* __restrict__ Wl,
    const float* __restrict__ bias, float* __restrict__ Cout, int ldc,
    int aClog, int aStride, int aBase,
    const float* __restrict__ hsb, const float* __restrict__ Cw,
    const float* __restrict__ Dp) {
  __shared__ unsigned short Ash[128 * 64];
  __shared__ unsigned short Asl[128 * 64];
  __shared__ unsigned short Bsh[128 * 64];
  __shared__ unsigned short Bsl[128 * 64];
  int tid = threadIdx.x;
  int n0 = blockIdx.x * 128, m0 = blockIdx.y * 128;
  int w = tid >> 6, lane = tid & 63;
  int wm = w & 1, wn = w >> 1;
  int lm = lane & 15, quad = lane >> 4;
  int sr = tid >> 3, scu = tid & 7;
  unsigned aMask = (1u << aClog) - 1u;
  floatx4 acc[4][4] = {};
  for (int kc = 0; kc < 4; ++kc) {
    float4 a0[4], a1[4];
    uint4 wh[4], wl[4];
#pragma unroll
    for (int p = 0; p < 4; ++p) {
      int am = m0 + sr + p * 32;
      int grow = ((am >> aClog) * aStride) + aBase + (int)((unsigned)am & aMask);
      const float* pa = A + (size_t)grow * 256 + kc * 64 + scu * 8;
      a0[p] = *(const float4*)pa;
      a1[p] = *(const float4*)(pa + 4);
      const unsigned short* pw = Wh + (size_t)(n0 + sr + p * 32) * 256 + kc * 64 + scu * 8;
      wh[p] = *(const uint4*)pw;
      wl[p] = *(const uint4*)(Wl + (pw - Wh));
    }
    __syncthreads();
#pragma unroll
    for (int p = 0; p < 4; ++p) {
      int r = sr + p * 32;
      int off = r * 64 + ((scu ^ (r & 7)) << 3);
      uint4 uh, ul;
      split8(a0[p], a1[p], uh, ul);
      *(uint4*)(Ash + off) = uh;
      *(uint4*)(Asl + off) = ul;
      *(uint4*)(Bsh + off) = wh[p];
      *(uint4*)(Bsl + off) = wl[p];
    }
    __syncthreads();
#pragma unroll
    for (int s = 0; s < 2; ++s) {
      shortx8 afh[4], afl[4], bfh[4], bfl[4];
#pragma unroll
      for (int i = 0; i < 4; ++i) {
        int rr = wm * 64 + i * 16 + lm;
        afh[i] = lds_frag(Ash, rr, s * 4 + quad);
        afl[i] = lds_frag(Asl, rr, s * 4 + quad);
      }
#pragma unroll
      for (int n = 0; n < 4; ++n) {
        int rr = wn * 64 + n * 16 + lm;
        bfh[n] = lds_frag(Bsh, rr, s * 4 + quad);
        bfl[n] = lds_frag(Bsl, rr, s * 4 + quad);
      }
#pragma unroll
      for (int i = 0; i < 4; ++i)
#pragma unroll
        for (int n = 0; n < 4; ++n) {
          acc[i][n] = mfma16(afl[i], bfh[n], acc[i][n]);
          acc[i][n] = mfma16(afh[i], bfl[n], acc[i][n]);
          acc[i][n] = mfma16(afh[i], bfh[n], acc[i][n]);
        }
    }
  }
  if (MODE == 2) {
    float cw[4][8], dp4[4], bi4[4];
#pragma unroll
    for (int n = 0; n < 4; ++n) {
      int col = n0 + wn * 64 + n * 16 + lm;
      float4 c0 = *(const float4*)(Cw + (size_t)col * 8);
      float4 c1 = *(const float4*)(Cw + (size_t)col * 8 + 4);
      cw[n][0] = c0.x; cw[n][1] = c0.y; cw[n][2] = c0.z; cw[n][3] = c0.w;
      cw[n][4] = c1.x; cw[n][5] = c1.y; cw[n][6] = c1.z; cw[n][7] = c1.w;
      dp4[n] = Dp[col];
      bi4[n] = bias[col];
    }
#pragma unroll
    for (int i = 0; i < 4; ++i)
#pragma unroll
      for (int r = 0; r < 4; ++r) {
        int row = m0 + wm * 64 + i * 16 + quad * 4 + r;
        const float* hp = hsb + (size_t)row * 8;
        float4 h0 = *(const float4*)hp;
        float4 h1 = *(const float4*)(hp + 4);
        float* srow = Cout + (size_t)row * 256;
        const float* xrow = A + (size_t)row * 256;
#pragma unroll
        for (int n = 0; n < 4; ++n) {
          int col = n0 + wn * 64 + n * 16 + lm;
          float xg = acc[i][n][r] + bi4[n];
          float gt = 1.0f / (1.0f + __expf(-xg));
          float y = dp4[n] * xrow[col];
          y += h0.x * cw[n][0] + h0.y * cw[n][1] + h0.z * cw[n][2] + h0.w * cw[n][3];
          y += h1.x * cw[n][4] + h1.y * cw[n][5] + h1.z * cw[n][6] + h1.w * cw[n][7];
          srow[col] += gt * y;
        }
      }
  } else {
#pragma unroll
    for (int i = 0; i < 4; ++i)
#pragma unroll
      for (int r = 0; r < 4; ++r) {
        int row = m0 + wm * 64 + i * 16 + quad * 4 + r;
#pragma unroll
        for (int n = 0; n < 4; ++n) {
          int col = n0 + wn * 64 + n * 16 + lm;
          float v = acc[i][n][r] + bias[col];
          if (MODE == 1) v = fmaxf(v, 0.0f);
          Cout[(size_t)row * ldc + col] = v;
        }
      }
  }
}

// ---------------- flash attention, split-bf16 QK / bf16 PV ----------------
__global__ __launch_bounds__(256, 2) void attn_k(
    const float* __restrict__ qb, const float* __restrict__ kvb,
    float* __restrict__ ob) {
  __shared__ unsigned short Qh[128 * 64];  // hi plane; wave rows reused for P
  __shared__ unsigned short Ql[128 * 64];
  __shared__ unsigned short Kh[64 * 64];
  __shared__ unsigned short Kl[64 * 64];
  __shared__ unsigned short Vt[64 * 64];   // V transposed [d][key], bf16-hi
  int tid = threadIdx.x;
  int bid = blockIdx.x;  // 8 qtiles * 4 heads * 16 batch
  int qt = bid & 7, bh = bid >> 3;
  int h = bh & 3, b = bh >> 2;
  int w = tid >> 6, lane = tid & 63, lm = lane & 15, quad = lane >> 4;
  int wrow = w * 32;
  int sr = tid >> 3, scu = tid & 7;
  const size_t qbase = ((size_t)(b * 1024 + qt * 128)) * 256 + h * 64;
#pragma unroll
  for (int p = 0; p < 4; ++p) {
    int r = sr + p * 32;
    const float* qrow = qb + qbase + (size_t)r * 256 + scu * 8;
    uint4 uh, ul;
    split8(*(const float4*)qrow, *(const float4*)(qrow + 4), uh, ul);
    int off = r * 64 + ((scu ^ (r & 7)) << 3);
    *(uint4*)(Qh + off) = uh;
    *(uint4*)(Ql + off) = ul;
  }
  __syncthreads();
  shortx8 qfh[2][2], qfl[2][2];
#pragma unroll
  for (int i = 0; i < 2; ++i)
#pragma unroll
    for (int s = 0; s < 2; ++s) {
      qfh[i][s] = lds_frag(Qh, wrow + i * 16 + lm, s * 4 + quad);
      qfl[i][s] = lds_frag(Ql, wrow + i * 16 + lm, s * 4 + quad);
    }
  float mrow[2][4], lrow[2][4];
  floatx4 oacc[2][4] = {};
#pragma unroll
  for (int i = 0; i < 2; ++i)
#pragma unroll
    for (int r = 0; r < 4; ++r) { mrow[i][r] = -3.0e38f; lrow[i][r] = 0.f; }
  const size_t kvbase = ((size_t)(b * 1024)) * 512 + h * 64;
  const float sc_l2 = 0.125f * 1.44269504089f;  // 1/sqrt(64) * log2(e)
  int vg = tid & 7, vk = (tid >> 3) * 2;
  for (int kt = 0; kt < 16; ++kt) {
    float4 k0[2], k1[2];
#pragma unroll
    for (int p = 0; p < 2; ++p) {
      int r = sr + p * 32;
      const float* krow = kvb + kvbase + (size_t)(kt * 64 + r) * 512 + scu * 8;
      k0[p] = *(const float4*)krow;
      k1[p] = *(const float4*)(krow + 4);
    }
    const float* vrow0 = kvb + kvbase + (size_t)(kt * 64 + vk) * 512 + 256 + vg * 8;
    const float* vrow1 = vrow0 + 512;
    float4 v00 = *(const float4*)vrow0, v01 = *(const float4*)(vrow0 + 4);
    float4 v10 = *(const float4*)vrow1, v11 = *(const float4*)(vrow1 + 4);
    __syncthreads();  // prior iter's K/V fragment reads complete
#pragma unroll
    for (int p = 0; p < 2; ++p) {
      int r = sr + p * 32;
      uint4 uh, ul;
      split8(k0[p], k1[p], uh, ul);
      int off = r * 64 + ((scu ^ (r & 7)) << 3);
      *(uint4*)(Kh + off) = uh;
      *(uint4*)(Kl + off) = ul;
    }
    {
      float f0[8] = {v00.x, v00.y, v00.z, v00.w, v01.x, v01.y, v01.z, v01.w};
      float f1[8] = {v10.x, v10.y, v10.z, v10.w, v11.x, v11.y, v11.z, v11.w};
#pragma unroll
      for (int j = 0; j < 8; ++j) {
        int d = vg * 8 + j;
        unsigned pack = ((unsigned)f2bf(f0[j])) | (((unsigned)f2bf(f1[j])) << 16);
        *(unsigned*)(Vt + d * 64 + (((vk >> 3) ^ (d & 7)) << 3) + (vk & 7)) = pack;
      }
    }
    __syncthreads();
    floatx4 sacc[2][4] = {};
#pragma unroll
    for (int s = 0; s < 2; ++s) {
      shortx8 kfh[4], kfl[4];
#pragma unroll
      for (int n = 0; n < 4; ++n) {
        kfh[n] = lds_frag(Kh, n * 16 + lm, s * 4 + quad);
        kfl[n] = lds_frag(Kl, n * 16 + lm, s * 4 + quad);
      }
#pragma unroll
      for (int i = 0; i < 2; ++i)
#pragma unroll
        for (int n = 0; n < 4; ++n) {
          sacc[i][n] = mfma16(qfl[i][s], kfh[n], sacc[i][n]);
          sacc[i][n] = mfma16(qfh[i][s], kfl[n], sacc[i][n]);
          sacc[i][n] = mfma16(qfh[i][s], kfh[n], sacc[i][n]);
        }
    }
#pragma unroll
    for (int i = 0; i < 2; ++i) {
#pragma unroll
      for (int r = 0; r < 4; ++r) {
        float t0 = sacc[i][0][r] * sc_l2, t1 = sacc[i][1][r] * sc_l2;
        float t2 = sacc[i][2][r] * sc_l2, t3 = sacc[i][3][r] * sc_l2;
        float rm = fmaxf(fmaxf(t0, t1), fmaxf(t2, t3));
#pragma unroll
        for (int mk = 1; mk < 16; mk <<= 1) rm = fmaxf(rm, __shfl_xor(rm, mk));
        float mnew = fmaxf(mrow[i][r], rm);
        float alpha = exp2f(mrow[i][r] - mnew);
        mrow[i][r] = mnew;
        float p0 = exp2f(t0 - mnew), p1 = exp2f(t1 - mnew);
        float p2 = exp2f(t2 - mnew), p3 = exp2f(t3 - mnew);
        float rsum = p0 + p1 + p2 + p3;
#pragma unroll
        for (int mk = 1; mk < 16; mk <<= 1) rsum += __shfl_xor(rsum, mk);
        lrow[i][r] = lrow[i][r] * alpha + rsum;
#pragma unroll
        for (int n = 0; n < 4; ++n) oacc[i][n][r] *= alpha;
        int prow = wrow + i * 16 + quad * 4 + r;
        float pv[4] = {p0, p1, p2, p3};
#pragma unroll
        for (int n = 0; n < 4; ++n) {
          int pcol = n * 16 + lm;
          Qh[prow * 64 + (((pcol >> 3) ^ (prow & 7)) << 3) + (pcol & 7)] = f2bf(pv[n]);
        }
      }
    }
#pragma unroll
    for (int s = 0; s < 2; ++s) {
      shortx8 pf[2], vf[4];
#pragma unroll
      for (int i = 0; i < 2; ++i) pf[i] = lds_frag(Qh, wrow + i * 16 + lm, s * 4 + quad);
#pragma unroll
      for (int n = 0; n < 4; ++n) vf[n] = lds_frag(Vt, n * 16 + lm, s * 4 + quad);
#pragma unroll
      for (int i = 0; i < 2; ++i)
#pragma unroll
        for (int n = 0; n < 4; ++n) oacc[i][n] = mfma16(pf[i], vf[n], oacc[i][n]);
    }
  }
  const size_t obase = ((size_t)(b * 1024 + qt * 128)) * 256 + h * 64;
#pragma unroll
  for (int i = 0; i < 2; ++i)
#pragma unroll
    for (int r = 0; r < 4; ++r) {
      int row = wrow + i * 16 + quad * 4 + r;
      float inv = 1.0f / lrow[i][r];
#pragma unroll
      for (int n = 0; n < 4; ++n)
        ob[obase + (size_t)row * 256 + n * 16 + lm] = oacc[i][n][r] * inv;
    }
}

// ---------------- weights fp32 -> split bf16 planes ----------------
__global__ __launch_bounds__(256) void wconv_k(
    const float* __restrict__ gw, const float* __restrict__ ipw,
    const float* __restrict__ ow, const float* __restrict__ d1w,
    unsigned short* __restrict__ dh, unsigned short* __restrict__ dl) {
  int i = (blockIdx.x * 256 + threadIdx.x) * 8;
  const float* src;
  if (i < 262144) src = gw + i;
  else if (i < 458752) src = ipw + (i - 262144);
  else if (i < 524288) src = ow + (i - 458752);
  else src = d1w + (i - 524288);
  uint4 uh, ul;
  split8(*(const float4*)src, *(const float4*)(src + 4), uh, ul);
  *(uint4*)(dh + i) = uh;
  *(uint4*)(dl + i) = ul;
}

// ---------------- final projection ----------------
__global__ __launch_bounds__(256) void dec2_k(const float* __restrict__ hb,
                                              const float* __restrict__ w2,
                                              const float* __restrict__ b2,
                                              float* __restrict__ out) {
  int tid = threadIdx.x;
  int m = blockIdx.x * 4 + (tid >> 6);
  int lane = tid & 63;
  float4 h4 = *(const float4*)(hb + (size_t)m * 256 + lane * 4);
  float4 w4 = *(const float4*)(w2 + lane * 4);
  float v = h4.x * w4.x + h4.y * w4.y + h4.z * w4.z + h4.w * w4.w;
  v = wave_sum64(v);
  if (lane == 0) out[m] = v + b2[0];
}

extern "C" void kernel_launch(void* const* d_in, const int* in_sizes, int n_in,
                              void* d_out, int out_size, void* d_ws, size_t ws_size,
                              hipStream_t stream) {
  const float* sparse_coords = (const float*)d_in[0];
  const float* sparse_values = (const float*)d_in[1];
  const float* query_coords  = (const float*)d_in[2];
  const float* t_arr         = (const float*)d_in[3];
  const float* noise         = (const float*)d_in[4];
  const float* B_f           = (const float*)d_in[5];
  const float* Wq_in         = (const float*)d_in[6];
  const float* bq_in         = (const float*)d_in[7];
  const float* Wi_in         = (const float*)d_in[8];
  const float* bi_in         = (const float*)d_in[9];
  const float* A_log         = (const float*)d_in[10];
  const float* Bw            = (const float*)d_in[11];
  const float* Cw            = (const float*)d_in[12];
  const float* Dp            = (const float*)d_in[13];
  const float* ln_g          = (const float*)d_in[14];
  const float* ln_b          = (const float*)d_in[15];
  const float* gate_w        = (const float*)d_in[16];
  const float* gate_b        = (const float*)d_in[17];
  const float* in_proj_w     = (const float*)d_in[18];
  const float* in_proj_b     = (const float*)d_in[19];
  const float* out_w         = (const float*)d_in[20];
  const float* out_b         = (const float*)d_in[21];
  const float* dec_w1        = (const float*)d_in[22];
  const float* dec_b1        = (const float*)d_in[23];
  const float* dec_w2        = (const float*)d_in[24];
  const float* dec_b2        = (const float*)d_in[25];

  float* fws = (float*)d_ws;
  float* seq  = fws;                    // 8,388,608 f
  float* xn   = seq + 8388608;          // 8,388,608 f
  float* qb   = xn + 8388608;           // 4,194,304 f
  float* kvb  = qb + 4194304;           // 8,388,608 f
  float* obuf = kvb + 8388608;          // 4,194,304 f
  float* Bu   = obuf + 4194304;         // 262,144 f
  float* hsb  = Bu + 262144;            // 262,144 f
  unsigned short* whi = (unsigned short*)(hsb + 262144);  // 589,824 us
  unsigned short* wlo = whi + 589824;                     // 589,824 us
  float* attb = xn;                     // xn dead after layer loop
  float* hrel = xn + 4194304;

  wconv_k<<<288, 256, 0, stream>>>(gate_w, in_proj_w, out_w, dec_w1, whi, wlo);
  embed_k<<<32768, 256, 0, stream>>>(sparse_coords, sparse_values, query_coords,
                                     t_arr, noise, B_f, Wq_in, bq_in, Wi_in, bi_in, seq);
  for (int l = 0; l < 4; ++l) {
    ln_bu_k<<<8192, 256, 0, stream>>>(seq, ln_g + l * 256, ln_b + l * 256,
                                      Bw + l * 2048, xn, Bu);
    scan_k<<<32, 256, 0, stream>>>(Bu, A_log + l * 8, hsb);
    mgemm_k<2><<<dim3(2, 256), 256, 0, stream>>>(
        xn, whi + l * 65536, wlo + l * 65536, gate_b + l * 256, seq, 256,
        30, 0, 0, hsb, Cw + l * 2048, Dp + l * 256);
  }
  // Q from query half (rows 1024..2047 of each batch)
  mgemm_k<0><<<dim3(2, 128), 256, 0, stream>>>(
      seq, whi + 262144, wlo + 262144, in_proj_b, qb, 256,
      10, 2048, 1024, nullptr, nullptr, nullptr);
  // K|V from input half (rows 0..1023), fused 512-wide output
  mgemm_k<0><<<dim3(4, 128), 256, 0, stream>>>(
      seq, whi + 327680, wlo + 327680, in_proj_b + 256, kvb, 512,
      10, 2048, 0, nullptr, nullptr, nullptr);
  attn_k<<<512, 256, 0, stream>>>(qb, kvb, obuf);
  mgemm_k<0><<<dim3(2, 128), 256, 0, stream>>>(
      obuf, whi + 458752, wlo + 458752, out_b, attb, 256,
      30, 0, 0, nullptr, nullptr, nullptr);
  mgemm_k<1><<<dim3(2, 128), 256, 0, stream>>>(
      attb, whi + 524288, wlo + 524288, dec_b1, hrel, 256,
      30, 0, 0, nullptr, nullptr, nullptr);
  dec2_k<<<4096, 256, 0, stream>>>(hrel, dec_w2, dec_b2, (float*)d_out);
}

// Round 4
// 718.807 us; speedup vs baseline: 1.6313x; 1.2079x over previous
//
#include <hip/hip_runtime.h>
#include <math.h>

// MAMBAFlow split-bf16 MFMA implementation, round 4.
// All matmuls (incl. embed) on mfma_f32_16x16x32_bf16 with 2-term bf16 splits:
//   a*b ~= ahi*bhi + ahi*blo + alo*bhi  (~2^-17 rel err, fp32-like)
// Producers emit split planes (ln_bu -> xn, QKV gemm -> q/k/v) so consumers
// load uint4 directly. Bu/hs transposed to [s][32768] for coalesced scan.

typedef float floatx4 __attribute__((ext_vector_type(4)));
typedef short shortx8 __attribute__((ext_vector_type(8)));

__device__ __forceinline__ unsigned short f2bf(float f) {
  unsigned u = __builtin_bit_cast(unsigned, f);
  u += 0x7FFFu + ((u >> 16) & 1u);  // RNE
  return (unsigned short)(u >> 16);
}
__device__ __forceinline__ float bf2f(unsigned short h) {
  unsigned u = ((unsigned)h) << 16;
  return __builtin_bit_cast(float, u);
}
__device__ __forceinline__ void split8(float4 a, float4 b, uint4& uh, uint4& ul) {
  float fv[8] = {a.x, a.y, a.z, a.w, b.x, b.y, b.z, b.w};
  unsigned hh[8], ll[8];
#pragma unroll
  for (int j = 0; j < 8; ++j) {
    unsigned short h = f2bf(fv[j]);
    hh[j] = h;
    ll[j] = f2bf(fv[j] - bf2f(h));
  }
  uh = make_uint4(hh[0] | (hh[1] << 16), hh[2] | (hh[3] << 16),
                  hh[4] | (hh[5] << 16), hh[6] | (hh[7] << 16));
  ul = make_uint4(ll[0] | (ll[1] << 16), ll[2] | (ll[3] << 16),
                  ll[4] | (ll[5] << 16), ll[6] | (ll[7] << 16));
}
__device__ __forceinline__ shortx8 lds_frag(const unsigned short* S, int row, int u) {
  uint4 v = *(const uint4*)(S + row * 64 + ((u ^ (row & 7)) << 3));
  return __builtin_bit_cast(shortx8, v);
}
__device__ __forceinline__ floatx4 mfma16(shortx8 a, shortx8 b, floatx4 c) {
  return __builtin_amdgcn_mfma_f32_16x16x32_bf16(a, b, c, 0, 0, 0);
}
__device__ __forceinline__ float wave_sum64(float v) {
#pragma unroll
  for (int m = 1; m < 64; m <<= 1) v += __shfl_xor(v, m);
  return v;
}

// ---------------- weights fp32 -> split bf16 planes (gate/inproj/out/dec1) ----------------
__global__ __launch_bounds__(256) void wconv_k(
    const float* __restrict__ gw, const float* __restrict__ ipw,
    const float* __restrict__ ow, const float* __restrict__ d1w,
    unsigned short* __restrict__ dh, unsigned short* __restrict__ dl) {
  int i = (blockIdx.x * 256 + threadIdx.x) * 8;
  const float* src;
  if (i < 262144) src = gw + i;
  else if (i < 458752) src = ipw + (i - 262144);
  else if (i < 524288) src = ow + (i - 458752);
  else src = d1w + (i - 524288);
  uint4 uh, ul;
  split8(*(const float4*)src, *(const float4*)(src + 4), uh, ul);
  *(uint4*)(dh + i) = uh;
  *(uint4*)(dl + i) = ul;
}

// ---------------- embed weights: Wi/Wq [256][33] -> split planes [2][256][64] (zero-pad) ----
__global__ __launch_bounds__(256) void wconv2_k(
    const float* __restrict__ Wi, const float* __restrict__ Wq,
    unsigned short* __restrict__ eh, unsigned short* __restrict__ el) {
  int idx = blockIdx.x * 256 + threadIdx.x;   // 0..32767, grid 128? -> 32768/256=128
  int sel = idx >> 14, rem = idx & 16383;
  int row = rem >> 6, k = rem & 63;
  float v = 0.f;
  if (k < 33) v = (sel ? Wq : Wi)[row * 33 + k];
  unsigned short h = f2bf(v);
  eh[idx] = h;
  el[idx] = f2bf(v - bf2f(h));
}

// ---------------- embed via MFMA: 64 tokens/block ----------------
__global__ __launch_bounds__(256) void embed_k(
    const float* __restrict__ sc, const float* __restrict__ sv,
    const float* __restrict__ qc, const float* __restrict__ tarr,
    const float* __restrict__ noise, const float* __restrict__ Bf,
    const float* __restrict__ bq, const float* __restrict__ bi,
    const unsigned short* __restrict__ Weh, const unsigned short* __restrict__ Wel,
    float* __restrict__ seq) {
  __shared__ unsigned short Ah[64 * 64];
  __shared__ unsigned short Al[64 * 64];
  __shared__ float teb[256];
  int tid = threadIdx.x;
  int bid = blockIdx.x;  // 16 chunk | half | b
  int chunk = bid & 15, half = (bid >> 4) & 1, b = bid >> 5;
  int rowbase = b * 2048 + half * 1024 + chunk * 64;
  // zero-init A planes (pad cols 33..63 must be 0)
  {
    uint4 z = make_uint4(0, 0, 0, 0);
    *(uint4*)(Ah + tid * 8) = z;            // 256*8 = 2048 us... need 4096: two stores
    *(uint4*)(Ah + 2048 + tid * 8) = z;
    *(uint4*)(Al + tid * 8) = z;
    *(uint4*)(Al + 2048 + tid * 8) = z;
  }
  // t-embed + bias into LDS
  {
    float t = tarr[b];
    int dd = tid & 127;
    float e = t * __expf((float)dd * -0.07252236513367074f);
    float v = (tid < 128) ? sinf(e) : cosf(e);
    teb[tid] = v + (half ? bq : bi)[tid];
  }
  __syncthreads();
  // fourier features: thread handles token tid>>2, freqs (tid&3)*4 .. +3
  {
    int tok = tid >> 2;
    int n = chunk * 64 + tok;
    const float* cp = (half ? qc : sc) + (size_t)(b * 1024 + n) * 2;
    float cx = cp[0], cy = cp[1];
#pragma unroll
    for (int jj = 0; jj < 4; ++jj) {
      int fr = (tid & 3) * 4 + jj;
      float px = cx * Bf[fr] + cy * Bf[16 + fr];
      float s = sinf(px), c = cosf(px);
      unsigned short sh = f2bf(s), ch = f2bf(c);
      int ks = fr, kc = 16 + fr;
      Ah[tok * 64 + (((ks >> 3) ^ (tok & 7)) << 3) + (ks & 7)] = sh;
      Al[tok * 64 + (((ks >> 3) ^ (tok & 7)) << 3) + (ks & 7)] = f2bf(s - bf2f(sh));
      Ah[tok * 64 + (((kc >> 3) ^ (tok & 7)) << 3) + (kc & 7)] = ch;
      Al[tok * 64 + (((kc >> 3) ^ (tok & 7)) << 3) + (kc & 7)] = f2bf(c - bf2f(ch));
    }
    if ((tid & 3) == 0) {  // value column k=32
      float vv = (half ? noise : sv)[b * 1024 + n];
      unsigned short vh = f2bf(vv);
      Ah[tok * 64 + ((4 ^ (tok & 7)) << 3)] = vh;
      Al[tok * 64 + ((4 ^ (tok & 7)) << 3)] = f2bf(vv - bf2f(vh));
    }
  }
  __syncthreads();
  int w = tid >> 6, lane = tid & 63, lm = lane & 15, quad = lane >> 4;
  const unsigned short* Wb = Weh + half * 16384;
  const unsigned short* Wbl = Wel + half * 16384;
  floatx4 acc[4][4] = {};
#pragma unroll
  for (int s = 0; s < 2; ++s) {
    shortx8 afh[4], afl[4];
#pragma unroll
    for (int i = 0; i < 4; ++i) {
      afh[i] = lds_frag(Ah, i * 16 + lm, s * 4 + quad);
      afl[i] = lds_frag(Al, i * 16 + lm, s * 4 + quad);
    }
#pragma unroll
    for (int n = 0; n < 4; ++n) {
      int wr = w * 64 + n * 16 + lm;
      shortx8 bh = __builtin_bit_cast(shortx8, *(const uint4*)(Wb + wr * 64 + (s * 4 + quad) * 8));
      shortx8 bl = __builtin_bit_cast(shortx8, *(const uint4*)(Wbl + wr * 64 + (s * 4 + quad) * 8));
#pragma unroll
      for (int i = 0; i < 4; ++i) {
        acc[i][n] = mfma16(afl[i], bh, acc[i][n]);
        acc[i][n] = mfma16(afh[i], bl, acc[i][n]);
        acc[i][n] = mfma16(afh[i], bh, acc[i][n]);
      }
    }
  }
#pragma unroll
  for (int i = 0; i < 4; ++i)
#pragma unroll
    for (int n = 0; n < 4; ++n) {
      int col = w * 64 + n * 16 + lm;
      float te = teb[col];
#pragma unroll
      for (int r = 0; r < 4; ++r) {
        int tok = i * 16 + quad * 4 + r;
        seq[(size_t)(rowbase + tok) * 256 + col] = acc[i][n][r] + te;
      }
    }
}

// ---------------- layernorm + split xn planes + transposed Bu ----------------
__global__ __launch_bounds__(256) void ln_bu_k(
    const float* __restrict__ seq, const float* __restrict__ g,
    const float* __restrict__ be, const float* __restrict__ Bw,
    unsigned short* __restrict__ xnh, unsigned short* __restrict__ xnl,
    float* __restrict__ BuT) {
  int tid = threadIdx.x;
  int row = blockIdx.x * 4 + (tid >> 6);
  int lane = tid & 63;
  float4 x = *(const float4*)(seq + (size_t)row * 256 + lane * 4);
  float s1 = x.x + x.y + x.z + x.w;
  float s2 = x.x * x.x + x.y * x.y + x.z * x.z + x.w * x.w;
#pragma unroll
  for (int mk = 1; mk < 64; mk <<= 1) {
    s1 += __shfl_xor(s1, mk);
    s2 += __shfl_xor(s2, mk);
  }
  float mu = s1 * (1.0f / 256.0f);
  float var = s2 * (1.0f / 256.0f) - mu * mu;
  float rs = rsqrtf(var + 1e-5f);
  float4 gg = *(const float4*)(g + lane * 4);
  float4 bb = *(const float4*)(be + lane * 4);
  float xn0 = (x.x - mu) * rs * gg.x + bb.x;
  float xn1 = (x.y - mu) * rs * gg.y + bb.y;
  float xn2 = (x.z - mu) * rs * gg.z + bb.z;
  float xn3 = (x.w - mu) * rs * gg.w + bb.w;
  unsigned short h0 = f2bf(xn0), h1 = f2bf(xn1), h2 = f2bf(xn2), h3 = f2bf(xn3);
  *(ushort4*)(xnh + (size_t)row * 256 + lane * 4) = make_ushort4(h0, h1, h2, h3);
  *(ushort4*)(xnl + (size_t)row * 256 + lane * 4) =
      make_ushort4(f2bf(xn0 - bf2f(h0)), f2bf(xn1 - bf2f(h1)),
                   f2bf(xn2 - bf2f(h2)), f2bf(xn3 - bf2f(h3)));
#pragma unroll
  for (int s = 0; s < 8; ++s) {
    float4 bw = *(const float4*)(Bw + s * 256 + lane * 4);
    float p = xn0 * bw.x + xn1 * bw.y + xn2 * bw.z + xn3 * bw.w;
#pragma unroll
    for (int mk = 1; mk < 64; mk <<= 1) p += __shfl_xor(p, mk);
    if (lane == 0) BuT[(size_t)s * 32768 + row] = p;
  }
}

// ---------------- SSM scan: one wave per (b,s), transposed coalesced layout ----------------
__global__ __launch_bounds__(256) void scan_k(
    const float* __restrict__ BuT, const float* __restrict__ A_log,
    float* __restrict__ hsT) {
  int tid = threadIdx.x;
  int wid = blockIdx.x * 4 + (tid >> 6);
  int lane = tid & 63;
  int b = wid >> 3, s = wid & 7;
  float A = -fminf(fmaxf(expf(A_log[s]), 1e-8f), 10.0f);
  float abar = expf(A * (1.0f / 2048.0f));
  size_t base = (size_t)s * 32768 + b * 2048 + lane * 32;
  const float4* bu4 = (const float4*)(BuT + base);
  float4 v[8];
#pragma unroll
  for (int k = 0; k < 8; ++k) v[k] = bu4[k];
  float bl = 0.f;
#pragma unroll
  for (int k = 0; k < 8; ++k) {
    bl = abar * bl + v[k].x;
    bl = abar * bl + v[k].y;
    bl = abar * bl + v[k].z;
    bl = abar * bl + v[k].w;
  }
  float a = expf(A * (32.0f / 2048.0f));
  float bb = bl;
#pragma unroll
  for (int off = 1; off < 64; off <<= 1) {
    float pa = __shfl_up(a, (unsigned)off);
    float pb = __shfl_up(bb, (unsigned)off);
    if (lane >= off) { bb = a * pb + bb; a = a * pa; }
  }
  float h = __shfl_up(bb, 1u);
  if (lane == 0) h = 0.f;
  float4* hp4 = (float4*)(hsT + base);
#pragma unroll
  for (int k = 0; k < 8; ++k) {
    float h0 = abar * h + v[k].x;
    float h1 = abar * h0 + v[k].y;
    float h2 = abar * h1 + v[k].z;
    float h3 = abar * h2 + v[k].w;
    hp4[k] = make_float4(h0, h1, h2, h3);
    h = h3;
  }
}

// ---------------- split-bf16 MFMA GEMM ----------------
// ASPLIT=1: A given as hi/lo ushort planes (row len 256). ASPLIT=0: A fp32.
// MODE 0: fp32 C=acc+bias   MODE 1: fp32 relu   MODE 2: gate-SSM epilogue into seq
// MODE 3: split-plane ushort outputs (Ch,Cl)
template <int MODE, int ASPLIT>
__global__ __launch_bounds__(256, 2) void mgemm_k(
    const void* __restrict__ Aptr, const unsigned short* __restrict__ Alp,
    const unsigned short* __restrict__ Wh, const unsigned short* __restrict__ Wl,
    const float* __restrict__ bias, void* __restrict__ C0, void* __restrict__ C1,
    int ldc, int aClog, int aStride, int aBase,
    const float* __restrict__ hsT, const float* __restrict__ Cw,
    const float* __restrict__ Dp) {
  __shared__ unsigned short Ash[128 * 64];
  __shared__ unsigned short Asl[128 * 64];
  __shared__ unsigned short Bsh[128 * 64];
  __shared__ unsigned short Bsl[128 * 64];
  int tid = threadIdx.x;
  int n0 = blockIdx.x * 128, m0 = blockIdx.y * 128;
  int w = tid >> 6, lane = tid & 63;
  int wm = w & 1, wn = w >> 1;
  int lm = lane & 15, quad = lane >> 4;
  int sr = tid >> 3, scu = tid & 7;
  unsigned aMask = (1u << aClog) - 1u;
  floatx4 acc[4][4] = {};
  for (int kc = 0; kc < 4; ++kc) {
    uint4 ah[4], al[4], wh[4], wl[4];
#pragma unroll
    for (int p = 0; p < 4; ++p) {
      int am = m0 + sr + p * 32;
      int grow = ((am >> aClog) * aStride) + aBase + (int)((unsigned)am & aMask);
      if (ASPLIT) {
        const unsigned short* pa = (const unsigned short*)Aptr + (size_t)grow * 256 + kc * 64 + scu * 8;
        ah[p] = *(const uint4*)pa;
        al[p] = *(const uint4*)(Alp + (pa - (const unsigned short*)Aptr));
      } else {
        const float* pa = (const float*)Aptr + (size_t)grow * 256 + kc * 64 + scu * 8;
        split8(*(const float4*)pa, *(const float4*)(pa + 4), ah[p], al[p]);
      }
      const unsigned short* pw = Wh + (size_t)(n0 + sr + p * 32) * 256 + kc * 64 + scu * 8;
      wh[p] = *(const uint4*)pw;
      wl[p] = *(const uint4*)(Wl + (pw - Wh));
    }
    __syncthreads();
#pragma unroll
    for (int p = 0; p < 4; ++p) {
      int r = sr + p * 32;
      int off = r * 64 + ((scu ^ (r & 7)) << 3);
      *(uint4*)(Ash + off) = ah[p];
      *(uint4*)(Asl + off) = al[p];
      *(uint4*)(Bsh + off) = wh[p];
      *(uint4*)(Bsl + off) = wl[p];
    }
    __syncthreads();
#pragma unroll
    for (int s = 0; s < 2; ++s) {
      shortx8 afh[4], afl[4], bfh[4], bfl[4];
#pragma unroll
      for (int i = 0; i < 4; ++i) {
        int rr = wm * 64 + i * 16 + lm;
        afh[i] = lds_frag(Ash, rr, s * 4 + quad);
        afl[i] = lds_frag(Asl, rr, s * 4 + quad);
      }
#pragma unroll
      for (int n = 0; n < 4; ++n) {
        int rr = wn * 64 + n * 16 + lm;
        bfh[n] = lds_frag(Bsh, rr, s * 4 + quad);
        bfl[n] = lds_frag(Bsl, rr, s * 4 + quad);
      }
#pragma unroll
      for (int i = 0; i < 4; ++i)
#pragma unroll
        for (int n = 0; n < 4; ++n) {
          acc[i][n] = mfma16(afl[i], bfh[n], acc[i][n]);
          acc[i][n] = mfma16(afh[i], bfl[n], acc[i][n]);
          acc[i][n] = mfma16(afh[i], bfh[n], acc[i][n]);
        }
    }
  }
  if (MODE == 2) {
    float cw[4][8], dp4[4], bi4[4];
#pragma unroll
    for (int n = 0; n < 4; ++n) {
      int col = n0 + wn * 64 + n * 16 + lm;
      float4 c0 = *(const float4*)(Cw + (size_t)col * 8);
      float4 c1 = *(const float4*)(Cw + (size_t)col * 8 + 4);
      cw[n][0] = c0.x; cw[n][1] = c0.y; cw[n][2] = c0.z; cw[n][3] = c0.w;
      cw[n][4] = c1.x; cw[n][5] = c1.y; cw[n][6] = c1.z; cw[n][7] = c1.w;
      dp4[n] = Dp[col];
      bi4[n] = bias[col];
    }
    float* seqp = (float*)C0;
    const unsigned short* Ahp = (const unsigned short*)Aptr;
#pragma unroll
    for (int i = 0; i < 4; ++i)
#pragma unroll
      for (int r = 0; r < 4; ++r) {
        int row = m0 + wm * 64 + i * 16 + quad * 4 + r;
        float hv[8];
#pragma unroll
        for (int s = 0; s < 8; ++s) hv[s] = hsT[(size_t)s * 32768 + row];
        float* srow = seqp + (size_t)row * 256;
#pragma unroll
        for (int n = 0; n < 4; ++n) {
          int col = n0 + wn * 64 + n * 16 + lm;
          float xg = acc[i][n][r] + bi4[n];
          float gt = 1.0f / (1.0f + __expf(-xg));
          float xv = bf2f(Ahp[(size_t)row * 256 + col]) + bf2f(Alp[(size_t)row * 256 + col]);
          float y = dp4[n] * xv;
#pragma unroll
          for (int s = 0; s < 8; ++s) y += hv[s] * cw[n][s];
          srow[col] += gt * y;
        }
      }
  } else if (MODE == 3) {
    unsigned short* Ch = (unsigned short*)C0;
    unsigned short* Cl = (unsigned short*)C1;
#pragma unroll
    for (int i = 0; i < 4; ++i)
#pragma unroll
      for (int r = 0; r < 4; ++r) {
        int row = m0 + wm * 64 + i * 16 + quad * 4 + r;
#pragma unroll
        for (int n = 0; n < 4; ++n) {
          int col = n0 + wn * 64 + n * 16 + lm;
          float v = acc[i][n][r] + bias[col];
          unsigned short h = f2bf(v);
          Ch[(size_t)row * ldc + col] = h;
          Cl[(size_t)row * ldc + col] = f2bf(v - bf2f(h));
        }
      }
  } else {
    float* Cf = (float*)C0;
#pragma unroll
    for (int i = 0; i < 4; ++i)
#pragma unroll
      for (int r = 0; r < 4; ++r) {
        int row = m0 + wm * 64 + i * 16 + quad * 4 + r;
#pragma unroll
        for (int n = 0; n < 4; ++n) {
          int col = n0 + wn * 64 + n * 16 + lm;
          float v = acc[i][n][r] + bias[col];
          if (MODE == 1) v = fmaxf(v, 0.0f);
          Cf[(size_t)row * ldc + col] = v;
        }
      }
  }
}

// ---------------- flash attention: split Q/K from planes, bf16 P/V ----------------
__global__ __launch_bounds__(256, 2) void attn_k(
    const unsigned short* __restrict__ qh, const unsigned short* __restrict__ ql,
    const unsigned short* __restrict__ kvh, const unsigned short* __restrict__ kvl,
    float* __restrict__ ob) {
  __shared__ unsigned short Qh[128 * 64];  // hi plane; wave rows reused for P
  __shared__ unsigned short Ql[128 * 64];
  __shared__ unsigned short Kh[64 * 64];
  __shared__ unsigned short Kl[64 * 64];
  __shared__ unsigned short Vt[64 * 64];   // V transposed [d][key], bf16-hi
  int tid = threadIdx.x;
  int bid = blockIdx.x;
  int qt = bid & 7, bh = bid >> 3;
  int h = bh & 3, b = bh >> 2;
  int w = tid >> 6, lane = tid & 63, lm = lane & 15, quad = lane >> 4;
  int wrow = w * 32;
  int sr = tid >> 3, scu = tid & 7;
  const size_t qbase = ((size_t)(b * 1024 + qt * 128)) * 256 + h * 64;
#pragma unroll
  for (int p = 0; p < 4; ++p) {
    int r = sr + p * 32;
    int off = r * 64 + ((scu ^ (r & 7)) << 3);
    *(uint4*)(Qh + off) = *(const uint4*)(qh + qbase + (size_t)r * 256 + scu * 8);
    *(uint4*)(Ql + off) = *(const uint4*)(ql + qbase + (size_t)r * 256 + scu * 8);
  }
  __syncthreads();
  shortx8 qfh[2][2], qfl[2][2];
#pragma unroll
  for (int i = 0; i < 2; ++i)
#pragma unroll
    for (int s = 0; s < 2; ++s) {
      qfh[i][s] = lds_frag(Qh, wrow + i * 16 + lm, s * 4 + quad);
      qfl[i][s] = lds_frag(Ql, wrow + i * 16 + lm, s * 4 + quad);
    }
  float mrow[2][4], lrow[2][4];
  floatx4 oacc[2][4] = {};
#pragma unroll
  for (int i = 0; i < 2; ++i)
#pragma unroll
    for (int r = 0; r < 4; ++r) { mrow[i][r] = -3.0e38f; lrow[i][r] = 0.f; }
  const size_t kvbase = ((size_t)(b * 1024)) * 512 + h * 64;
  const float sc_l2 = 0.125f * 1.44269504089f;
  int vg = tid & 7, vk = (tid >> 3) * 2;
  for (int kt = 0; kt < 16; ++kt) {
    uint4 kh4[2], kl4[2];
#pragma unroll
    for (int p = 0; p < 2; ++p) {
      int r = sr + p * 32;
      size_t a = kvbase + (size_t)(kt * 64 + r) * 512 + scu * 8;
      kh4[p] = *(const uint4*)(kvh + a);
      kl4[p] = *(const uint4*)(kvl + a);
    }
    uint4 vv0 = *(const uint4*)(kvh + kvbase + (size_t)(kt * 64 + vk) * 512 + 256 + vg * 8);
    uint4 vv1 = *(const uint4*)(kvh + kvbase + (size_t)(kt * 64 + vk + 1) * 512 + 256 + vg * 8);
    __syncthreads();
#pragma unroll
    for (int p = 0; p < 2; ++p) {
      int r = sr + p * 32;
      int off = r * 64 + ((scu ^ (r & 7)) << 3);
      *(uint4*)(Kh + off) = kh4[p];
      *(uint4*)(Kl + off) = kl4[p];
    }
    {
      shortx8 s0 = __builtin_bit_cast(shortx8, vv0);
      shortx8 s1 = __builtin_bit_cast(shortx8, vv1);
#pragma unroll
      for (int j = 0; j < 8; ++j) {
        int d = vg * 8 + j;
        unsigned pack = ((unsigned)(unsigned short)s0[j]) |
                        (((unsigned)(unsigned short)s1[j]) << 16);
        *(unsigned*)(Vt + d * 64 + (((vk >> 3) ^ (d & 7)) << 3) + (vk & 7)) = pack;
      }
    }
    __syncthreads();
    floatx4 sacc[2][4] = {};
#pragma unroll
    for (int s = 0; s < 2; ++s) {
      shortx8 kfh[4], kfl[4];
#pragma unroll
      for (int n = 0; n < 4; ++n) {
        kfh[n] = lds_frag(Kh, n * 16 + lm, s * 4 + quad);
        kfl[n] = lds_frag(Kl, n * 16 + lm, s * 4 + quad);
      }
#pragma unroll
      for (int i = 0; i < 2; ++i)
#pragma unroll
        for (int n = 0; n < 4; ++n) {
          sacc[i][n] = mfma16(qfl[i][s], kfh[n], sacc[i][n]);
          sacc[i][n] = mfma16(qfh[i][s], kfl[n], sacc[i][n]);
          sacc[i][n] = mfma16(qfh[i][s], kfh[n], sacc[i][n]);
        }
    }
#pragma unroll
    for (int i = 0; i < 2; ++i) {
#pragma unroll
      for (int r = 0; r < 4; ++r) {
        float t0 = sacc[i][0][r] * sc_l2, t1 = sacc[i][1][r] * sc_l2;
        float t2 = sacc[i][2][r] * sc_l2, t3 = sacc[i][3][r] * sc_l2;
        float rm = fmaxf(fmaxf(t0, t1), fmaxf(t2, t3));
#pragma unroll
        for (int mk = 1; mk < 16; mk <<= 1) rm = fmaxf(rm, __shfl_xor(rm, mk));
        float mnew = fmaxf(mrow[i][r], rm);
        float alpha = exp2f(mrow[i][r] - mnew);
        mrow[i][r] = mnew;
        float p0 = exp2f(t0 - mnew), p1 = exp2f(t1 - mnew);
        float p2 = exp2f(t2 - mnew), p3 = exp2f(t3 - mnew);
        float rsum = p0 + p1 + p2 + p3;
#pragma unroll
        for (int mk = 1; mk < 16; mk <<= 1) rsum += __shfl_xor(rsum, mk);
        lrow[i][r] = lrow[i][r] * alpha + rsum;
#pragma unroll
        for (int n = 0; n < 4; ++n) oacc[i][n][r] *= alpha;
        int prow = wrow + i * 16 + quad * 4 + r;
        float pv[4] = {p0, p1, p2, p3};
#pragma unroll
        for (int n = 0; n < 4; ++n) {
          int pcol = n * 16 + lm;
          Qh[prow * 64 + (((pcol >> 3) ^ (prow & 7)) << 3) + (pcol & 7)] = f2bf(pv[n]);
        }
      }
    }
#pragma unroll
    for (int s = 0; s < 2; ++s) {
      shortx8 pf[2], vf[4];
#pragma unroll
      for (int i = 0; i < 2; ++i) pf[i] = lds_frag(Qh, wrow + i * 16 + lm, s * 4 + quad);
#pragma unroll
      for (int n = 0; n < 4; ++n) vf[n] = lds_frag(Vt, n * 16 + lm, s * 4 + quad);
#pragma unroll
      for (int i = 0; i < 2; ++i)
#pragma unroll
        for (int n = 0; n < 4; ++n) oacc[i][n] = mfma16(pf[i], vf[n], oacc[i][n]);
    }
  }
  const size_t obase = ((size_t)(b * 1024 + qt * 128)) * 256 + h * 64;
#pragma unroll
  for (int i = 0; i < 2; ++i)
#pragma unroll
    for (int r = 0; r < 4; ++r) {
      int row = wrow + i * 16 + quad * 4 + r;
      float inv = 1.0f / lrow[i][r];
#pragma unroll
      for (int n = 0; n < 4; ++n)
        ob[obase + (size_t)row * 256 + n * 16 + lm] = oacc[i][n][r] * inv;
    }
}

// ---------------- final projection ----------------
__global__ __launch_bounds__(256) void dec2_k(const float* __restrict__ hb,
                                              const float* __restrict__ w2,
                                              const float* __restrict__ b2,
                                              float* __restrict__ out) {
  int tid = threadIdx.x;
  int m = blockIdx.x * 4 + (tid >> 6);
  int lane = tid & 63;
  float4 h4 = *(const float4*)(hb + (size_t)m * 256 + lane * 4);
  float4 w4 = *(const float4*)(w2 + lane * 4);
  float v = h4.x * w4.x + h4.y * w4.y + h4.z * w4.z + h4.w * w4.w;
  v = wave_sum64(v);
  if (lane == 0) out[m] = v + b2[0];
}

extern "C" void kernel_launch(void* const* d_in, const int* in_sizes, int n_in,
                              void* d_out, int out_size, void* d_ws, size_t ws_size,
                              hipStream_t stream) {
  const float* sparse_coords = (const float*)d_in[0];
  const float* sparse_values = (const float*)d_in[1];
  const float* query_coords  = (const float*)d_in[2];
  const float* t_arr         = (const float*)d_in[3];
  const float* noise         = (const float*)d_in[4];
  const float* B_f           = (const float*)d_in[5];
  const float* Wq_in         = (const float*)d_in[6];
  const float* bq_in         = (const float*)d_in[7];
  const float* Wi_in         = (const float*)d_in[8];
  const float* bi_in         = (const float*)d_in[9];
  const float* A_log         = (const float*)d_in[10];
  const float* Bw            = (const float*)d_in[11];
  const float* Cw            = (const float*)d_in[12];
  const float* Dp            = (const float*)d_in[13];
  const float* ln_g          = (const float*)d_in[14];
  const float* ln_b          = (const float*)d_in[15];
  const float* gate_w        = (const float*)d_in[16];
  const float* gate_b        = (const float*)d_in[17];
  const float* in_proj_w     = (const float*)d_in[18];
  const float* in_proj_b     = (const float*)d_in[19];
  const float* out_w         = (const float*)d_in[20];
  const float* out_b         = (const float*)d_in[21];
  const float* dec_w1        = (const float*)d_in[22];
  const float* dec_b1        = (const float*)d_in[23];
  const float* dec_w2        = (const float*)d_in[24];
  const float* dec_b2        = (const float*)d_in[25];

  unsigned short* us = (unsigned short*)d_ws;
  float* seq = (float*)us;                 // 8,388,608 f = 16,777,216 us
  unsigned short* xnh = us + 16777216;     // 8,388,608
  unsigned short* xnl = xnh + 8388608;     // 8,388,608
  unsigned short* qhp = xnl + 8388608;     // 4,194,304
  unsigned short* qlp = qhp + 4194304;     // 4,194,304
  unsigned short* kvh = qlp + 4194304;     // 8,388,608
  unsigned short* kvl = kvh + 8388608;     // 8,388,608
  float* BuT = (float*)(kvl + 8388608);    // 262,144 f
  float* hsT = BuT + 262144;               // 262,144 f
  unsigned short* whi = (unsigned short*)(hsT + 262144);  // 589,824
  unsigned short* wlo = whi + 589824;      // 589,824
  unsigned short* Weh = wlo + 589824;      // 32,768
  unsigned short* Wel = Weh + 32768;       // 32,768
  float* obuf = (float*)xnh;               // alias: xn planes dead after layers
  float* attb = (float*)xnl;
  float* hrel = (float*)qhp;               // q planes dead after attn

  wconv_k<<<288, 256, 0, stream>>>(gate_w, in_proj_w, out_w, dec_w1, whi, wlo);
  wconv2_k<<<128, 256, 0, stream>>>(Wi_in, Wq_in, Weh, Wel);
  embed_k<<<512, 256, 0, stream>>>(sparse_coords, sparse_values, query_coords,
                                   t_arr, noise, B_f, bq_in, bi_in, Weh, Wel, seq);
  for (int l = 0; l < 4; ++l) {
    ln_bu_k<<<8192, 256, 0, stream>>>(seq, ln_g + l * 256, ln_b + l * 256,
                                      Bw + l * 2048, xnh, xnl, BuT);
    scan_k<<<32, 256, 0, stream>>>(BuT, A_log + l * 8, hsT);
    mgemm_k<2, 1><<<dim3(2, 256), 256, 0, stream>>>(
        xnh, xnl, whi + l * 65536, wlo + l * 65536, gate_b + l * 256, seq, nullptr,
        256, 30, 0, 0, hsT, Cw + l * 2048, Dp + l * 256);
  }
  mgemm_k<3, 0><<<dim3(2, 128), 256, 0, stream>>>(
      seq, nullptr, whi + 262144, wlo + 262144, in_proj_b, qhp, qlp,
      256, 10, 2048, 1024, nullptr, nullptr, nullptr);
  mgemm_k<3, 0><<<dim3(4, 128), 256, 0, stream>>>(
      seq, nullptr, whi + 327680, wlo + 327680, in_proj_b + 256, kvh, kvl,
      512, 10, 2048, 0, nullptr, nullptr, nullptr);
  attn_k<<<512, 256, 0, stream>>>(qhp, qlp, kvh, kvl, obuf);
  mgemm_k<0, 0><<<dim3(2, 128), 256, 0, stream>>>(
      obuf, nullptr, whi + 458752, wlo + 458752, out_b, attb, nullptr,
      256, 30, 0, 0, nullptr, nullptr, nullptr);
  mgemm_k<1, 0><<<dim3(2, 128), 256, 0, stream>>>(
      attb, nullptr, whi + 524288, wlo + 524288, dec_b1, hrel, nullptr,
      256, 30, 0, 0, nullptr, nullptr, nullptr);
  dec2_k<<<4096, 256, 0, stream>>>(hrel, dec_w2, dec_b2, (float*)d_out);
}